// Round 9
// baseline (217.381 us; speedup 1.0000x reference)
//
#include <hip/hip_runtime.h>

// PMField R15b: resubmit of R15 (round 8 bench failed: container infra error,
// no kernel signal). Software-pipeline S(c+1) over G(c), double-buffered w.
//  - R14 confirmed VALU-issue sensitivity (pk-f32: 182->157us), but VALUBusy
//    FELL to 49%: remaining wall is exposed latency in the serial per-chunk
//    chain  sA read -> S-MFMA -> elementwise -> w pack/write -> wf read ->
//    G-MFMA  at ~2-4 effective waves/SIMD.
//  - S(c+1) is independent of G(c); only collision is the shared w-plane
//    buffer. So: 2 w-buffers (sWF[4][8][64], 32KB), per-chunk body issues
//    {wf reads + ga loads} FIRST, then runs S(c+1) (trans/VALU heavy, ~400cy)
//    to cover those latencies, then G-MFMA(c). z staging reuses buf1
//    (safe: zf consumed into regs before S(1) overwrites buf1; wave-internal
//    DS in-order -- validated R5..R14).
//  - LDS 64KB (sA 32 + sWF 32): occupancy proven irrelevant R8/R10/R12.
//    (256,2) kept -- the only cap that never spilled. Tripwire: VGPR<=128 or
//    WRITE_SIZE >> 33MB => spill, void.
//  - Keeps all R14 math: pk-f32 elementwise, acc-init fold, v_perm packs,
//    f32 cn2/mu, no barriers (wave-private DS, in-order).
// Layouts (HW-verified): C/D col=lane&15,row=q*4+r; A[m=lane&15][k=q*8+j];
// B = transpose-dual of A.

#define STEPS 8
#define DTB   0.15f
#define EPSF  1e-4f

typedef short bf16x8 __attribute__((ext_vector_type(8)));
typedef float f32x4  __attribute__((ext_vector_type(4)));
typedef float f32x2  __attribute__((ext_vector_type(2)));
union FragU { int4 i; bf16x8 h; };

__device__ __forceinline__ f32x2 max2(f32x2 a, f32x2 b) {
    return __builtin_elementwise_max(a, b);
}
__device__ __forceinline__ f32x2 min2(f32x2 a, f32x2 b) {
    return __builtin_elementwise_min(a, b);
}

// byte-select pack: r = [lo.b2, lo.b3, hi.b2, hi.b3]  (one v_perm_b32)
__device__ __forceinline__ unsigned bfpt(float lo, float hi) { // trunc pack
    return __builtin_amdgcn_perm(__float_as_uint(hi), __float_as_uint(lo),
                                 0x07060302u);
}
__device__ __forceinline__ unsigned bfp(float lo, float hi) {  // round pack
    return __builtin_amdgcn_perm(__float_as_uint(hi) + 0x8000u,
                                 __float_as_uint(lo) + 0x8000u, 0x07060302u);
}

// d_ws layout:
//   int4 [0,    2048)  S-planes: ((c*4+Mt)*2+h)*64 + lane = bf16x8 of -2C[center][dims]
//   int4 [2048, 4096)  G-planes: ((Mt*4+c)*2+h)*64 + lane = bf16x8 of C^T[dim][centers]
//   f32  ws[16384..16640)  cn2[256]   (|c|^2, full precision)
//   f32  ws[16640..16896)  mu[256]
__global__ void pm_prep(const float* __restrict__ centers,
                        const float* __restrict__ mus,
                        unsigned* __restrict__ ws) {
    const int gtid = blockIdx.x * 256 + threadIdx.x;
    if (gtid < 2048) {                       // S-plane frags
        const int c = gtid >> 9, Mt = (gtid >> 7) & 3, h = (gtid >> 6) & 1;
        const int L = gtid & 63, m16 = L & 15, q = L >> 4;
        const float* row = centers + (size_t)(64 * c + 16 * Mt + m16) * 64 + 32 * h + 8 * q;
        uint4 u;
        u.x = bfp(-2.f * row[0], -2.f * row[1]);
        u.y = bfp(-2.f * row[2], -2.f * row[3]);
        u.z = bfp(-2.f * row[4], -2.f * row[5]);
        u.w = bfp(-2.f * row[6], -2.f * row[7]);
        ((uint4*)ws)[gtid] = u;
    } else if (gtid < 4096) {                // G-plane frags (C^T)
        const int i = gtid - 2048;
        const int Mt = i >> 9, c = (i >> 7) & 3, h = (i >> 6) & 1;
        const int L = i & 63, m16 = L & 15, q = L >> 4;
        const float* base = centers + (size_t)(64 * c + 32 * h + 8 * q) * 64 + 16 * Mt + m16;
        uint4 u;
        u.x = bfp(base[0],   base[64]);
        u.y = bfp(base[128], base[192]);
        u.z = bfp(base[256], base[320]);
        u.w = bfp(base[384], base[448]);
        ((uint4*)ws)[gtid] = u;
    } else if (gtid < 4352) {                // cn2 / mu as f32
        const int t = gtid - 4096;
        const float* r = centers + (size_t)t * 64;
        float a0 = 0.f, a1 = 0.f, a2 = 0.f, a3 = 0.f;
#pragma unroll
        for (int d = 0; d < 64; d += 4) {
            a0 = fmaf(r[d],     r[d],     a0);
            a1 = fmaf(r[d + 1], r[d + 1], a1);
            a2 = fmaf(r[d + 2], r[d + 2], a2);
            a3 = fmaf(r[d + 3], r[d + 3], a3);
        }
        float c2 = (a0 + a1) + (a2 + a3);
        ((float*)ws)[16384 + t] = c2;
        ((float*)ws)[16640 + t] = mus[t];
    }
}

// ---- per-chunk phase macros (wave-private, no barriers) ----
// S phase for chunk c_: S-MFMA + packed elementwise, w -> (wpu_)
#define S_PHASE(c_, wpu_)                                                      \
  {                                                                            \
    const f32x2 eps2 = (f32x2){EPSF, EPSF};                                    \
    _Pragma("unroll")                                                          \
    for (int Mt = 0; Mt < 4; ++Mt) {                                           \
      FragU a0, a1;                                                            \
      a0.i = sA[(((c_) * 4 + Mt) * 2 + 0) * 64 + lane];                        \
      a1.i = sA[(((c_) * 4 + Mt) * 2 + 1) * 64 + lane];                        \
      const float4 cn4 = *(const float4*)(wsC  + 64 * (c_) + 16 * Mt + 4 * q); \
      const float4 mu4 = *(const float4*)(wsMu + 64 * (c_) + 16 * Mt + 4 * q); \
      const f32x2 cnlo = (f32x2){cn4.x, cn4.y}, cnhi = (f32x2){cn4.z, cn4.w};  \
      const f32x2 mulo = (f32x2){mu4.x, mu4.y}, muhi = (f32x2){mu4.z, mu4.w};  \
      f32x4 S[2];                                                              \
      _Pragma("unroll")                                                        \
      for (int Nt = 0; Nt < 2; ++Nt) {                                         \
        const f32x2 zz2 = (f32x2){zzp[Nt], zzp[Nt]};                           \
        const f32x2 i0 = zz2 + cnlo, i1 = zz2 + cnhi;                          \
        f32x4 acc = (f32x4){i0.x, i0.y, i1.x, i1.y};                           \
        acc = __builtin_amdgcn_mfma_f32_16x16x32_bf16(a0.h, zf[0][Nt].h, acc, 0, 0, 0); \
        acc = __builtin_amdgcn_mfma_f32_16x16x32_bf16(a1.h, zf[1][Nt].h, acc, 0, 0, 0); \
        S[Nt] = acc;                                                           \
      }                                                                        \
      const int Kt = Mt >> 1;                                                  \
      const int qt = (2 * Mt + (q >> 1)) & 3;                                  \
      _Pragma("unroll")                                                        \
      for (int Nt = 0; Nt < 2; ++Nt) {                                         \
        f32x2 s0 = (f32x2){S[Nt][0], S[Nt][1]};                                \
        f32x2 s1 = (f32x2){S[Nt][2], S[Nt][3]};                                \
        f32x2 r20 = max2(s0, eps2);                                            \
        f32x2 r21 = max2(s1, eps2);                                            \
        f32x2 rin0, rin1;                                                      \
        rin0.x = __builtin_amdgcn_rsqf(r20.x);                                 \
        rin0.y = __builtin_amdgcn_rsqf(r20.y);                                 \
        rin1.x = __builtin_amdgcn_rsqf(r21.x);                                 \
        rin1.y = __builtin_amdgcn_rsqf(r21.y);                                 \
        f32x2 mur0 = mulo * rin0, mur1 = muhi * rin1;                          \
        nacc2[Nt] += mur0; nacc2[Nt] += mur1;                                  \
        f32x2 q0 = rin0 * rin0, q1 = rin1 * rin1;                              \
        f32x2 wv0 = mur0 * q0,  wv1 = mur1 * q1;                               \
        swp2[Nt] += wv0; swp2[Nt] += wv1;                                      \
        const int pos = ((Kt * 2 + Nt) * 64 + m16 + 16 * qt) * 4 + 2 * (q & 1);\
        *(uint2*)((wpu_) + pos) = make_uint2(bfpt(wv0.x, wv0.y),               \
                                             bfpt(wv1.x, wv1.y));              \
      }                                                                        \
    }                                                                          \
  }

// G loads for chunk c_: wf frags from (wfb_) + ga frags from L2 (issue early)
#define G_LOAD(c_, wfb_)                                                       \
  _Pragma("unroll")                                                            \
  for (int Kt = 0; Kt < 2; ++Kt)                                               \
    _Pragma("unroll")                                                          \
    for (int Nt = 0; Nt < 2; ++Nt)                                             \
      wf[Kt][Nt].i = (wfb_)[(Kt * 2 + Nt) * 64 + lane];                        \
  _Pragma("unroll")                                                            \
  for (int Mt = 0; Mt < 4; ++Mt) {                                             \
    ga[Mt][0].i = wsG[((Mt * 4 + (c_)) * 2 + 0) * 64 + lane];                  \
    ga[Mt][1].i = wsG[((Mt * 4 + (c_)) * 2 + 1) * 64 + lane];                  \
  }

#define G_MFMA()                                                               \
  _Pragma("unroll")                                                            \
  for (int Mt = 0; Mt < 4; ++Mt)                                               \
    _Pragma("unroll")                                                          \
    for (int Nt = 0; Nt < 2; ++Nt) {                                           \
      g[Mt][Nt] = __builtin_amdgcn_mfma_f32_16x16x32_bf16(ga[Mt][0].h, wf[0][Nt].h, g[Mt][Nt], 0, 0, 0); \
      g[Mt][Nt] = __builtin_amdgcn_mfma_f32_16x16x32_bf16(ga[Mt][1].h, wf[1][Nt].h, g[Mt][Nt], 0, 0, 0); \
    }

__global__ __launch_bounds__(256, 2)
void pm_main(const float* __restrict__ z_in,
             const unsigned* __restrict__ ws,
             float* __restrict__ z_out) {
    __shared__ int4 sA[2048];          // 32 KB: S-plane frags, block-shared
    __shared__ int4 sWF[4][8][64];     // 32 KB: per-wave 2x4 w/z B-frag planes

    const int4* wsA = (const int4*)ws;
    const int4* wsG = wsA + 2048;             // G-plane frags (L2-resident)
    const float* wsC  = (const float*)ws + 16384;
    const float* wsMu = (const float*)ws + 16640;

    const int tid  = threadIdx.x;
    const int lane = tid & 63;
    const int w    = tid >> 6;
    const int m16  = lane & 15;
    const int q    = lane >> 4;

    // copy S planes to LDS (lane-linear, coalesced, conflict-free)
#pragma unroll
    for (int i = 0; i < 8; ++i) sA[i * 256 + tid] = wsA[i * 256 + tid];
    __syncthreads();

    const int pbase = blockIdx.x * 128;   // 128 particles/block, 32/wave

    // z state in C/D layout: lane holds dims {16Mt+4q..+3} x particles {m16, m16+16}
    f32x4 z[4][2];
#pragma unroll
    for (int Mt = 0; Mt < 4; ++Mt)
#pragma unroll
        for (int Nt = 0; Nt < 2; ++Nt)
            z[Mt][Nt] = *(const f32x4*)(z_in + (size_t)(pbase + 32 * w + m16 + 16 * Nt) * 64
                                        + 16 * Mt + 4 * q);

    int4* const wavebuf = &sWF[w][0][0];             // 8 planes, wave-private

#pragma unroll 1
    for (int s = 0; s < STEPS; ++s) {
        // zz per particle (pk pairs + butterfly over q groups)
        float zzp[2];
#pragma unroll
        for (int Nt = 0; Nt < 2; ++Nt) {
            f32x2 a2 = (f32x2){0.f, 0.f};
#pragma unroll
            for (int Mt = 0; Mt < 4; ++Mt) {
                f32x2 lo = (f32x2){z[Mt][Nt][0], z[Mt][Nt][1]};
                f32x2 hi = (f32x2){z[Mt][Nt][2], z[Mt][Nt][3]};
                a2 += lo * lo;
                a2 += hi * hi;
            }
            float a = a2.x + a2.y;
            a += __shfl_xor(a, 16, 64);
            a += __shfl_xor(a, 32, 64);
            zzp[Nt] = a;
        }

        // z (C/D regs) -> buf1 planes (4..7): scatter write, then zf read
        {
            unsigned* zstage = (unsigned*)(wavebuf + 4 * 64);
#pragma unroll
            for (int Mt = 0; Mt < 4; ++Mt) {
                const int Kt = Mt >> 1;
                const int qt = (2 * Mt + (q >> 1)) & 3;
#pragma unroll
                for (int Nt = 0; Nt < 2; ++Nt) {
                    const int pos = ((Kt * 2 + Nt) * 64 + m16 + 16 * qt) * 4 + 2 * (q & 1);
                    *(uint2*)(zstage + pos) = make_uint2(bfp(z[Mt][Nt][0], z[Mt][Nt][1]),
                                                         bfp(z[Mt][Nt][2], z[Mt][Nt][3]));
                }
            }
        }
        FragU zf[2][2];
#pragma unroll
        for (int Kt = 0; Kt < 2; ++Kt)
#pragma unroll
            for (int Nt = 0; Nt < 2; ++Nt)
                zf[Kt][Nt].i = wavebuf[4 * 64 + (Kt * 2 + Nt) * 64 + lane];

        f32x4 g[4][2];
#pragma unroll
        for (int Mt = 0; Mt < 4; ++Mt)
#pragma unroll
            for (int Nt = 0; Nt < 2; ++Nt) g[Mt][Nt] = (f32x4){0.f, 0.f, 0.f, 0.f};
        f32x2 nacc2[2] = {(f32x2){0.f, 0.f}, (f32x2){0.f, 0.f}};
        f32x2 swp2[2]  = {(f32x2){0.f, 0.f}, (f32x2){0.f, 0.f}};

        // ---- pipelined chunk loop: S(0); [G_LOAD(c) | S(c+1) | G_MFMA(c)]; G(3)
        S_PHASE(0, (unsigned*)wavebuf)            // w(0) -> buf0 (planes 0..3)

#pragma unroll 1
        for (int c = 0; c < 3; ++c) {
            int4* bufA = wavebuf + (c & 1) * (4 * 64);                 // G src
            unsigned* bufB = (unsigned*)(wavebuf + ((c + 1) & 1) * (4 * 64));
            FragU wf[2][2], ga[4][2];
            G_LOAD(c, bufA)        // issue wf ds_reads + ga L2 loads early
            S_PHASE(c + 1, bufB)   // heavy trans/VALU block covers the latency
            G_MFMA()
        }
        {
            int4* bufA = wavebuf + 1 * (4 * 64);   // S(3) wrote buf1
            FragU wf[2][2], ga[4][2];
            G_LOAD(3, bufA)
            G_MFMA()
        }

        // reduce n, sw across q groups; packed z update
        float tco[2], swf[2];
#pragma unroll
        for (int Nt = 0; Nt < 2; ++Nt) {
            float a = nacc2[Nt].x + nacc2[Nt].y;
            a += __shfl_xor(a, 16, 64);
            a += __shfl_xor(a, 32, 64);
            float b = swp2[Nt].x + swp2[Nt].y;
            b += __shfl_xor(b, 16, 64);
            b += __shfl_xor(b, 32, 64);
            tco[Nt] = DTB * __builtin_amdgcn_rcpf(1.f + a);
            swf[Nt] = b;
        }
        const f32x2 lo2 = (f32x2){-3.f, -3.f}, hi2 = (f32x2){3.f, 3.f};
#pragma unroll
        for (int Mt = 0; Mt < 4; ++Mt)
#pragma unroll
            for (int Nt = 0; Nt < 2; ++Nt) {
                const f32x2 sw2 = (f32x2){swf[Nt], swf[Nt]};
                const f32x2 tc2 = (f32x2){tco[Nt], tco[Nt]};
#pragma unroll
                for (int p = 0; p < 2; ++p) {
                    f32x2 zp = (f32x2){z[Mt][Nt][2 * p], z[Mt][Nt][2 * p + 1]};
                    f32x2 gp = (f32x2){g[Mt][Nt][2 * p], g[Mt][Nt][2 * p + 1]};
                    f32x2 gd = gp - sw2 * zp;          // pk_fma
                    f32x2 zn = zp + tc2 * gd;          // pk_fma
                    zn = min2(max2(zn, lo2), hi2);     // pk_max + pk_min
                    z[Mt][Nt][2 * p]     = zn.x;
                    z[Mt][Nt][2 * p + 1] = zn.y;
                }
            }
    }

    // direct C/D-layout store (16B segments, rows covered across lanes)
#pragma unroll
    for (int Mt = 0; Mt < 4; ++Mt)
#pragma unroll
        for (int Nt = 0; Nt < 2; ++Nt)
            *(f32x4*)(z_out + (size_t)(pbase + 32 * w + m16 + 16 * Nt) * 64
                      + 16 * Mt + 4 * q) = z[Mt][Nt];
}

extern "C" void kernel_launch(void* const* d_in, const int* in_sizes, int n_in,
                              void* d_out, int out_size, void* d_ws, size_t ws_size,
                              hipStream_t stream) {
    const float* z       = (const float*)d_in[0];
    const float* centers = (const float*)d_in[1];
    const float* mus     = (const float*)d_in[2];
    float* out           = (float*)d_out;
    unsigned* ws         = (unsigned*)d_ws;

    pm_prep<<<dim3(17), dim3(256), 0, stream>>>(centers, mus, ws);
    // 131072 particles / 128 per block (4 waves x 32) = 1024 blocks
    pm_main<<<dim3(1024), dim3(256), 0, stream>>>(z, ws, out);
}